// Round 4
// baseline (218.605 us; speedup 1.0000x reference)
//
#include <hip/hip_runtime.h>
#include <math.h>

#define Bn   16
#define Cn   512
#define Nn   1024
#define Gn   8
#define CPG  64
#define EPSf 1e-5f

typedef short           bf16x8 __attribute__((ext_vector_type(8)));
typedef float           f32x4  __attribute__((ext_vector_type(4)));
typedef unsigned short  u16;
typedef unsigned short  u16x4  __attribute__((ext_vector_type(4)));
typedef unsigned short  u16x8  __attribute__((ext_vector_type(8)));

#define TS 136   // LDS repack row stride (u16): 272B rows, 16B-aligned, 2-way banks

__device__ __forceinline__ u16 f2b(float f) {
  union { float f; unsigned u; } c; c.f = f;
  unsigned r = (c.u + 0x7FFFu + ((c.u >> 16) & 1u)) >> 16;
  return (u16)r;
}

// async 16B global -> LDS DMA; LDS dest = wave-uniform base + lane*16
__device__ __forceinline__ void g2l16(const void* g, void* l) {
  __builtin_amdgcn_global_load_lds(
      (const __attribute__((address_space(1))) unsigned int*)g,
      (__attribute__((address_space(3))) unsigned int*)l, 16, 0, 0);
}

// raw barrier: same instruction as __syncthreads but WITHOUT the compiler's
// s_waitcnt vmcnt(0) drain; "memory" clobber = compiler-level fence.
__device__ __forceinline__ void barrier_asm() {
  asm volatile("s_barrier" ::: "memory");
}

// ---------------------------------------------------------------------------
// OLD GEMM core (BK=32, 128x128, 4 waves): only used by gnw2's W2 GEMM now.
__device__ __forceinline__ void gemm_core(u16* As, u16* Bs,
    const u16* __restrict__ A, size_t sA,
    const u16* __restrict__ B, size_t sB, int K, f32x4 acc[4][4]) {
  const int t = threadIdx.x;
  const int w = t >> 6, l = t & 63, quad = l >> 4, lr = l & 15;
  const int wm = (w >> 1) * 64, wn = (w & 1) * 64;

  const int ra = w * 16 + (l >> 2);
  const int p  = l & 3;
  const int q  = p ^ ((ra >> 1) & 3);
  const u16* gA0 = A + (size_t)ra * sA + q * 8;
  const u16* gA1 = A + (size_t)(ra + 64) * sA + q * 8;
  const u16* gB0 = B + (size_t)ra * sB + q * 8;
  const u16* gB1 = B + (size_t)(ra + 64) * sB + q * 8;
  u16* lA0 = As + ra * 32 + p * 8;
  u16* lA1 = As + (ra + 64) * 32 + p * 8;
  u16* lB0 = Bs + ra * 32 + p * 8;
  u16* lB1 = Bs + (ra + 64) * 32 + p * 8;

  for (int k0 = 0; k0 < K; k0 += 32) {
    __syncthreads();
    g2l16(gA0 + k0, lA0);
    g2l16(gA1 + k0, lA1);
    g2l16(gB0 + k0, lB0);
    g2l16(gB1 + k0, lB1);
    __syncthreads();
    bf16x8 af[4], bfr[4];
    #pragma unroll
    for (int fm = 0; fm < 4; fm++) {
      int r = wm + fm * 16 + lr;
      af[fm] = *(const bf16x8*)&As[r * 32 + ((quad ^ ((r >> 1) & 3)) << 3)];
    }
    #pragma unroll
    for (int fn = 0; fn < 4; fn++) {
      int r = wn + fn * 16 + lr;
      bfr[fn] = *(const bf16x8*)&Bs[r * 32 + ((quad ^ ((r >> 1) & 3)) << 3)];
    }
    #pragma unroll
    for (int fm = 0; fm < 4; fm++)
      #pragma unroll
      for (int fn = 0; fn < 4; fn++)
        acc[fm][fn] = __builtin_amdgcn_mfma_f32_16x16x32_bf16(
            af[fm], bfr[fn], acc[fm][fn], 0, 0, 0);
  }
}

#define GEMM_PRE()                                              \
  const int t = threadIdx.x;                                    \
  const int w = t >> 6, l = t & 63, quad = l >> 4, lr = l & 15; \
  const int wm = (w >> 1) * 64, wn = (w & 1) * 64;              \
  (void)w; (void)wm; (void)wn; (void)l;                         \
  f32x4 acc[4][4];                                              \
  { f32x4 z = {0.f, 0.f, 0.f, 0.f};                             \
    for (int i_ = 0; i_ < 4; i_++)                              \
      for (int j_ = 0; j_ < 4; j_++) acc[i_][j_] = z; }

// ---------------------------------------------------------------------------
// core256: 256(m) x 128(n) block tile, 4 waves (2x2 grid of 128x64 wave
// tiles), BK=32, 3-slot LDS ring, DEPTH-2 prefetch with POST-BARRIER staging,
// counted vmcnt(6), single raw barrier per K-step, setprio (T3/T4/T5).
//
// Order per iteration t:  vmcnt(6) -> barrier -> stage(t+2) -> compute(t).
// Post-barrier staging makes S=3 safe at depth 2: when stage(t+2) issues,
// every wave has passed barrier(t), so compute(t-1) is globally done and
// slot (t+2)%3 == (t-1)%3 is free. A fast wave's stage(t+3) sits behind
// barrier(t+1), which slow waves reach only after their ds_read(t).
// vmcnt: at iteration t only stage(t+1) (6 loads) may be outstanding, so
// vmcnt(6) proves tile t landed; last iteration (no t+1) uses vmcnt(0).
#define SLOT 12288

__device__ __forceinline__ void core256(const u16* __restrict__ A, size_t sA,
    const u16* __restrict__ B, size_t sB, int K, u16* SH, f32x4 acc[8][4],
    int wm, int wn, int quad, int lr) {
  const int t = threadIdx.x, wv = t >> 6, l = t & 63;
  const int srow = l >> 2;                       // row-within-16-row chunk
  const int sch  = ((l & 3) ^ ((l >> 3) & 3)) * 8;  // pre-swizzled src chunk

  const u16* gA[4]; int lA[4];
  const u16* gB[2]; int lB[2];
  #pragma unroll
  for (int c = 0; c < 4; c++) {                  // A rows wv*64+c*16+srow
    gA[c] = A + (size_t)(wv * 64 + c * 16 + srow) * sA + sch;
    lA[c] = wv * 2048 + c * 512 + l * 8;         // = base + lane*16B: linear
  }
  #pragma unroll
  for (int c = 0; c < 2; c++) {                  // B rows wv*32+c*16+srow
    gB[c] = B + (size_t)(wv * 32 + c * 16 + srow) * sB + sch;
    lB[c] = 8192 + wv * 1024 + c * 512 + l * 8;
  }

  u16 *sc = SH, *sn = SH + SLOT, *sf = SH + 2 * SLOT;
  const int nt = K >> 5;
  // prologue: stage tile 0 -> slot0, tile 1 -> slot1
  #pragma unroll
  for (int c = 0; c < 4; c++) g2l16(gA[c], sc + lA[c]);
  #pragma unroll
  for (int c = 0; c < 2; c++) g2l16(gB[c], sc + lB[c]);
  if (nt > 1) {
    #pragma unroll
    for (int c = 0; c < 4; c++) g2l16(gA[c] + 32, sn + lA[c]);
    #pragma unroll
    for (int c = 0; c < 2; c++) g2l16(gB[c] + 32, sn + lB[c]);
  }

  const int rch = (quad ^ ((lr >> 1) & 3)) * 8;  // frag read chunk (swizzled)
  int aoff[8], boff[4];
  #pragma unroll
  for (int fm = 0; fm < 8; fm++) aoff[fm] = (wm + fm * 16 + lr) * 32 + rch;
  #pragma unroll
  for (int fn = 0; fn < 4; fn++) boff[fn] = 8192 + (wn + fn * 16 + lr) * 32 + rch;

  for (int tt = 0; tt < nt; tt++) {
    if (tt + 1 < nt) {                           // stage(t+1) may stay in flight
      asm volatile("s_waitcnt vmcnt(6)" ::: "memory");   // tile t landed
    } else {
      asm volatile("s_waitcnt vmcnt(0)" ::: "memory");
    }
    barrier_asm();                               // single barrier per K-step
    if (tt + 2 < nt) {                           // stage tile t+2 into sf
      const int k0 = (tt + 2) * 32;
      #pragma unroll
      for (int c = 0; c < 4; c++) g2l16(gA[c] + k0, sf + lA[c]);
      #pragma unroll
      for (int c = 0; c < 2; c++) g2l16(gB[c] + k0, sf + lB[c]);
    }
    bf16x8 af[8], bfr[4];
    #pragma unroll
    for (int fm = 0; fm < 8; fm++) af[fm] = *(const bf16x8*)&sc[aoff[fm]];
    #pragma unroll
    for (int fn = 0; fn < 4; fn++) bfr[fn] = *(const bf16x8*)&sc[boff[fn]];
    __builtin_amdgcn_s_setprio(1);
    #pragma unroll
    for (int fm = 0; fm < 8; fm++)
      #pragma unroll
      for (int fn = 0; fn < 4; fn++)
        acc[fm][fn] = __builtin_amdgcn_mfma_f32_16x16x32_bf16(
            af[fm], bfr[fn], acc[fm][fn], 0, 0, 0);
    __builtin_amdgcn_s_setprio(0);
    u16* tmp = sc; sc = sn; sn = sf; sf = tmp;   // rotate ring
  }
}

#define CORE256_PRE()                                             \
  const int t = threadIdx.x;                                      \
  const int w = t >> 6, l = t & 63, quad = l >> 4, lr = l & 15;   \
  const int wm = (w >> 1) * 128, wn = (w & 1) * 64;               \
  (void)l;                                                        \
  f32x4 acc[8][4];                                                \
  { f32x4 z = {0.f, 0.f, 0.f, 0.f};                               \
    _Pragma("unroll")                                             \
    for (int i_ = 0; i_ < 8; i_++)                                \
      _Pragma("unroll")                                           \
      for (int j_ = 0; j_ < 4; j_++) acc[i_][j_] = z; }

// ---------------------------------------------------------------------------
// core128: 128x128 block tile, 4 waves (2x2 of 64x64), BK=32, 4-slot LDS
// ring, prefetch depth 2 (vmcnt(8)), single raw barrier per K-step, setprio.
// Same address math / swizzle as gemm_core; same per-element K order.
// Ring safety (S=4, d=2): stage(t+2) writes slot (t-2)%4, whose readers all
// finished compute(t-2) before barrier(t-1), which this wave has passed.
#define SLOT128 8192   // u16 per slot: A[128][32] @0, B[128][32] @4096

__device__ __forceinline__ void core128(const u16* __restrict__ A, size_t sA,
    const u16* __restrict__ B, size_t sB, int K, u16* SH, f32x4 acc[4][4],
    int wm, int wn, int quad, int lr) {
  const int t = threadIdx.x;
  const int w = t >> 6, l = t & 63;
  const int ra = w * 16 + (l >> 2);              // [0,64)
  const int p  = l & 3;
  const int q  = p ^ ((ra >> 1) & 3);            // pre-swizzled src chunk
  const u16* gA0 = A + (size_t)ra * sA + q * 8;
  const u16* gA1 = A + (size_t)(ra + 64) * sA + q * 8;
  const u16* gB0 = B + (size_t)ra * sB + q * 8;
  const u16* gB1 = B + (size_t)(ra + 64) * sB + q * 8;
  const int lA0 = ra * 32 + p * 8;               // linear: wave base + lane*16B
  const int lA1 = (ra + 64) * 32 + p * 8;
  const int lB0 = 4096 + ra * 32 + p * 8;
  const int lB1 = 4096 + (ra + 64) * 32 + p * 8;

  const int nt = K >> 5;
  // prologue: stage tiles 0,1
  {
    u16* s0 = SH;
    g2l16(gA0, s0 + lA0); g2l16(gA1, s0 + lA1);
    g2l16(gB0, s0 + lB0); g2l16(gB1, s0 + lB1);
    if (nt > 1) {
      u16* s1 = SH + SLOT128;
      g2l16(gA0 + 32, s1 + lA0); g2l16(gA1 + 32, s1 + lA1);
      g2l16(gB0 + 32, s1 + lB0); g2l16(gB1 + 32, s1 + lB1);
    }
  }
  const int rch = (quad ^ ((lr >> 1) & 3)) * 8;  // frag read chunk (swizzled)
  int aoff[4], boff[4];
  #pragma unroll
  for (int fm = 0; fm < 4; fm++) aoff[fm] = (wm + fm * 16 + lr) * 32 + rch;
  #pragma unroll
  for (int fn = 0; fn < 4; fn++) boff[fn] = 4096 + (wn + fn * 16 + lr) * 32 + rch;

  for (int tt = 0; tt < nt; tt++) {
    u16* sc = SH + (tt & 3) * SLOT128;
    if (tt + 2 < nt) {                           // stage tile t+2
      u16* sn = SH + ((tt + 2) & 3) * SLOT128;
      const int k0 = (tt + 2) * 32;
      g2l16(gA0 + k0, sn + lA0); g2l16(gA1 + k0, sn + lA1);
      g2l16(gB0 + k0, sn + lB0); g2l16(gB1 + k0, sn + lB1);
      asm volatile("s_waitcnt vmcnt(8)" ::: "memory");   // tile t landed;
    } else if (tt + 1 < nt) {                            // t+1,t+2 in flight
      asm volatile("s_waitcnt vmcnt(4)" ::: "memory");
    } else {
      asm volatile("s_waitcnt vmcnt(0)" ::: "memory");
    }
    barrier_asm();                               // single barrier per K-step
    bf16x8 af[4], bfr[4];
    #pragma unroll
    for (int fm = 0; fm < 4; fm++) af[fm] = *(const bf16x8*)&sc[aoff[fm]];
    #pragma unroll
    for (int fn = 0; fn < 4; fn++) bfr[fn] = *(const bf16x8*)&sc[boff[fn]];
    __builtin_amdgcn_s_setprio(1);
    #pragma unroll
    for (int fm = 0; fm < 4; fm++)
      #pragma unroll
      for (int fn = 0; fn < 4; fn++)
        acc[fm][fn] = __builtin_amdgcn_mfma_f32_16x16x32_bf16(
            af[fm], bfr[fn], acc[fm][fn], 0, 0, 0);
    __builtin_amdgcn_s_setprio(0);
  }
}

// ---------------------------------------------------------------------------
// prep: [0,512) qk-weight cvt | [512,576) WvT transpose-cvt | [576,578) bias2
//       | [578,1090) gn-stats partial raw sums (atomic) | [1090,1346) proj_w cvt
__global__ __launch_bounds__(256) void prep_k(const float* __restrict__ qkv_w,
    const float* __restrict__ proj_w, const float* __restrict__ qkv_b,
    const float* __restrict__ x, u16* __restrict__ wqk16,
    u16* __restrict__ wvT16, u16* __restrict__ pw16,
    float* __restrict__ bias2, float* __restrict__ stats) {
  __shared__ u16 T[64][68];
  __shared__ float redf[8];
  int bid = blockIdx.x, t = threadIdx.x;
  if (bid < 512) {                       // q,k weights: 131072 float4 exact
    int i = bid * 256 + t;
    float4 v = ((const float4*)qkv_w)[i];
    u16x4 o;
    o.x = f2b(v.x); o.y = f2b(v.y); o.z = f2b(v.z); o.w = f2b(v.w);
    ((u16x4*)wqk16)[i] = o;
  } else if (bid < 576) {                // WvT[d][c] = Wv[c][d] bf16
    int tile = bid - 512, tx = tile & 7, ty = tile >> 3;
    int row = t >> 4, col4 = t & 15;
    #pragma unroll
    for (int it = 0; it < 4; it++) {
      int cc = row + it * 16;
      float4 v = *(const float4*)&qkv_w[(size_t)(1024 + ty * 64 + cc) * 512 + tx * 64 + col4 * 4];
      u16x4 o;
      o.x = f2b(v.x); o.y = f2b(v.y); o.z = f2b(v.z); o.w = f2b(v.w);
      *(u16x4*)&T[cc][col4 * 4] = o;
    }
    __syncthreads();
    #pragma unroll
    for (int it = 0; it < 2; it++) {
      int ch = t + it * 256;
      int d = ch >> 3, c8 = (ch & 7) * 8;
      u16x8 o;
      #pragma unroll
      for (int j = 0; j < 8; j++) o[j] = T[c8 + j][d];
      *(u16x8*)&wvT16[(size_t)(tx * 64 + d) * 512 + ty * 64 + c8] = o;
    }
  } else if (bid < 578) {                // bias2 = proj_w @ v_bias (fp32 exact)
    int m = (bid - 576) * 256 + t;
    float s = 0.f;
    for (int c = 0; c < 512; c++)
      s += proj_w[(size_t)m * 512 + c] * qkv_b[1024 + c];
    bias2[m] = s;
  } else if (bid < 1090) {               // gn raw-sum partials: 4 blocks/(b,g)
    int idx = bid - 578, bg = idx >> 2, part = idx & 3;
    const float4* xp = (const float4*)x + (size_t)bg * 16384 + part * 4096;
    float s = 0.f, ss = 0.f;
    for (int i = t; i < 4096; i += 256) {
      float4 v = xp[i];
      s  += v.x + v.y + v.z + v.w;
      ss += v.x * v.x + v.y * v.y + v.z * v.z + v.w * v.w;
    }
    #pragma unroll
    for (int off = 32; off > 0; off >>= 1) {
      s  += __shfl_down(s, off);
      ss += __shfl_down(ss, off);
    }
    int lane = t & 63, wid = t >> 6;
    if (lane == 0) { redf[wid] = s; redf[4 + wid] = ss; }
    __syncthreads();
    if (t == 0) {
      atomicAdd(&stats[bg],       redf[0] + redf[1] + redf[2] + redf[3]);
      atomicAdd(&stats[128 + bg], redf[4] + redf[5] + redf[6] + redf[7]);
    }
  } else {                               // proj_w cvt: 65536 float4
    int i = (bid - 1090) * 256 + t;
    float4 v = ((const float4*)proj_w)[i];
    u16x4 o;
    o.x = f2b(v.x); o.y = f2b(v.y); o.z = f2b(v.z); o.w = f2b(v.w);
    ((u16x4*)pw16)[i] = o;
  }
}

// ---------------------------------------------------------------------------
// gnw2: [0,16) W2 = pw16 @ Wv | [16,2064) gn apply+transpose (raw-sum stats)
__global__ __launch_bounds__(256) void gnw2_k(const float* __restrict__ x,
    const float* __restrict__ stats, const float* __restrict__ nw,
    const float* __restrict__ nb, const u16* __restrict__ pw16,
    const u16* __restrict__ wvT16, u16* __restrict__ W2, u16* __restrict__ hT) {
  __shared__ u16 AsBs[8192];
  int bid = blockIdx.x;
  if (bid < 16) {
    int m0 = (bid >> 2) * 128, d0 = (bid & 3) * 128;
    GEMM_PRE();
    gemm_core(AsBs, AsBs + 4096, pw16 + (size_t)m0 * 512, 512,
              wvT16 + (size_t)d0 * 512, 512, 512, acc);
    #pragma unroll
    for (int fm = 0; fm < 4; fm++) {
      int m = m0 + wm + fm * 16 + quad * 4;
      #pragma unroll
      for (int fn = 0; fn < 4; fn++) {
        int d = d0 + wn + fn * 16 + lr;
        f32x4 a = acc[fm][fn];
        W2[(size_t)(m    ) * 512 + d] = f2b(a[0]);
        W2[(size_t)(m + 1) * 512 + d] = f2b(a[1]);
        W2[(size_t)(m + 2) * 512 + d] = f2b(a[2]);
        W2[(size_t)(m + 3) * 512 + d] = f2b(a[3]);
      }
    }
    return;
  }
  int u = bid - 16;                      // 2048 tiles: 64c x 64n
  int b = u >> 7, rem = u & 127, c0 = (rem >> 4) * 64, n0 = (rem & 15) * 64;
  u16 (*T)[68] = (u16(*)[68])AsBs;
  int t = threadIdx.x;
  int row = t >> 4, col4 = t & 15;
  const float inv = 1.0f / 65536.0f;
  #pragma unroll
  for (int it = 0; it < 4; it++) {
    int cc = row + it * 16;
    int c  = c0 + cc;
    int bg = b * Gn + (c >> 6);
    float mean = stats[bg] * inv;
    float var  = stats[128 + bg] * inv - mean * mean;
    float rstd = rsqrtf(var + EPSf);
    float a  = nw[c] * rstd;
    float bb = nb[c] - mean * a;
    float4 xv = *(const float4*)&x[((size_t)(b * Cn + c)) * Nn + n0 + col4 * 4];
    u16x4 o;
    o.x = f2b(xv.x * a + bb); o.y = f2b(xv.y * a + bb);
    o.z = f2b(xv.z * a + bb); o.w = f2b(xv.w * a + bb);
    *(u16x4*)&T[cc][col4 * 4] = o;
  }
  __syncthreads();
  #pragma unroll
  for (int it = 0; it < 2; it++) {
    int ch = t + it * 256;
    int n  = ch >> 3, c8 = (ch & 7) * 8;
    u16x8 o;
    #pragma unroll
    for (int j = 0; j < 8; j++) o[j] = T[c8 + j][n];
    *(u16x8*)&hT[((size_t)(b * Nn + n0 + n)) * 512 + c0 + c8] = o;
  }
}

// ---------------------------------------------------------------------------
// qkvp (256x128 tiles, 768 blocks):
//   [0,512)   qkT[b][n][m] = wqk.h + bias : 16b x 4 m-tiles(256) x 8 n-tiles(128)
//   [512,768) VP = W2 @ h               : 16b x 2 m-tiles(256) x 8 j-tiles(128)
__global__ __launch_bounds__(256, 2) void qkvp_k(const u16* __restrict__ wqk16,
    const u16* __restrict__ W2, const u16* __restrict__ hT,
    const float* __restrict__ qkv_b, u16* __restrict__ qkT,
    u16* __restrict__ VP) {
  __shared__ __align__(16) u16 SH[3 * SLOT];   // 73728 B: ring + epilogue T
  int u = blockIdx.x;
  CORE256_PRE();

  if (u < 512) {                         // ---- qkT: transpose-store epilogue
    int b = u >> 5, rem = u & 31, m0 = (rem >> 3) * 256, n0 = (rem & 7) * 128;
    core256(wqk16 + (size_t)m0 * 512, 512,
            hT + (size_t)(b * Nn + n0) * 512, 512, 512, SH, acc, wm, wn, quad, lr);
    float4 bss[8];
    #pragma unroll
    for (int fm = 0; fm < 8; fm++)
      bss[fm] = *(const float4*)&qkv_b[m0 + wm + fm * 16 + quad * 4];
    u16* T = SH;                         // overlay [64 n][264 m-stride] u16
    const int hsel = wn >> 6;            // which n-half this wave owns
    #pragma unroll
    for (int h = 0; h < 2; h++) {
      barrier_asm();                     // (first one also closes the K-loop)
      if (hsel == h) {
        #pragma unroll
        for (int fm = 0; fm < 8; fm++) {
          int mc = wm + fm * 16 + quad * 4;
          #pragma unroll
          for (int fn = 0; fn < 4; fn++) {
            int nl = fn * 16 + lr;
            f32x4 a = acc[fm][fn];
            u16x4 pk;
            pk.x = f2b(a[0] + bss[fm].x); pk.y = f2b(a[1] + bss[fm].y);
            pk.z = f2b(a[2] + bss[fm].z); pk.w = f2b(a[3] + bss[fm].w);
            *(u16x4*)&T[nl * 264 + mc] = pk;   // T[n][m], 264-stride (2-way banks)
          }
        }
      }
      barrier_asm();
      #pragma unroll
      for (int kk = 0; kk < 8; kk++) {   // flush 64 rows x 256 m, coalesced
        int idx = t + 256 * kk, row = idx >> 5, grp = idx & 31;
        u16x8 v = *(u16x8*)&T[row * 264 + grp * 8];
        *(u16x8*)&qkT[((size_t)(b * Nn + n0 + h * 64 + row)) * 1024 + m0 + grp * 8] = v;
      }
    }
  } else {                               // ---- VP: natural-store epilogue
    int u2 = u - 512;
    int b = u2 >> 4, rem = u2 & 15, m0 = (rem >> 3) * 256, j0 = (rem & 7) * 128;
    core256(W2 + (size_t)m0 * 512, 512,
            hT + (size_t)(b * Nn + j0) * 512, 512, 512, SH, acc, wm, wn, quad, lr);
    u16* T = SH;                         // overlay [128 m][TS] u16
    const int hsel = wm >> 7;            // which m-half this wave owns
    #pragma unroll
    for (int h = 0; h < 2; h++) {
      barrier_asm();
      if (hsel == h) {
        #pragma unroll
        for (int fm = 0; fm < 8; fm++) {
          int ml = fm * 16 + quad * 4;   // m within 128-half
          #pragma unroll
          for (int fn = 0; fn < 4; fn++) {
            int jl = wn + fn * 16 + lr;
            f32x4 a = acc[fm][fn];
            T[(ml    ) * TS + jl] = f2b(a[0]);
            T[(ml + 1) * TS + jl] = f2b(a[1]);
            T[(ml + 2) * TS + jl] = f2b(a[2]);
            T[(ml + 3) * TS + jl] = f2b(a[3]);
          }
        }
      }
      barrier_asm();
      #pragma unroll
      for (int kk = 0; kk < 8; kk++) {   // flush 128 rows x 128 j, coalesced
        int idx = t + 256 * kk, row = idx >> 4, grp = idx & 15;
        u16x8 v = *(u16x8*)&T[row * TS + grp * 8];
        *(u16x8*)&VP[((size_t)(b * 512 + m0 + h * 128 + row)) * 1024 + j0 + grp * 8] = v;
      }
    }
  }
}

// ---------------------------------------------------------------------------
// qkexp (256x128 tiles, 512 blocks): Pm = exp(scale*q.k) bf16 unnormalized;
// rpart partial row sums. exp computed ONCE per element, fused into the
// half-tile repack phase. No max subtraction: logits ~ N(0,1).
__global__ __launch_bounds__(256, 2) void qkexp_k(const u16* __restrict__ qkT,
    u16* __restrict__ Pm, float* __restrict__ rpart) {
  __shared__ __align__(16) u16 SH[3 * SLOT];
  __shared__ float psum[256];
  int u = blockIdx.x;
  int b = u >> 5, rem = u & 31, i0 = (rem >> 3) * 256, j0 = (rem & 7) * 128;
  const u16* base = qkT + (size_t)b * Nn * 1024;
  CORE256_PRE();
  core256(base + (size_t)i0 * 1024, 1024,
          base + (size_t)j0 * 1024 + 512, 1024, 512, SH, acc, wm, wn, quad, lr);
  psum[t] = 0.f;
  const float scale = 0.04419417382415922f;  // 512^-0.5
  u16* T = SH;                           // overlay [128 i][TS] u16
  const int hsel = wm >> 7;              // which i-half this wave owns
  #pragma unroll
  for (int h = 0; h < 2; h++) {
    barrier_asm();                       // protects T reuse AND psum init
    if (hsel == h) {
      #pragma unroll
      for (int fm = 0; fm < 8; fm++) {
        int il = fm * 16 + quad * 4;     // i within 128-half
        float rs0 = 0.f, rs1 = 0.f, rs2 = 0.f, rs3 = 0.f;
        #pragma unroll
        for (int fn = 0; fn < 4; fn++) {
          int jl = wn + fn * 16 + lr;
          f32x4 a = acc[fm][fn];
          float e0 = __expf(a[0] * scale);
          float e1 = __expf(a[1] * scale);
          float e2 = __expf(a[2] * scale);
          float e3 = __expf(a[3] * scale);
          rs0 += e0; rs1 += e1; rs2 += e2; rs3 += e3;
          T[(il    ) * TS + jl] = f2b(e0);
          T[(il + 1) * TS + jl] = f2b(e1);
          T[(il + 2) * TS + jl] = f2b(e2);
          T[(il + 3) * TS + jl] = f2b(e3);
        }
        #pragma unroll
        for (int mask = 1; mask < 16; mask <<= 1) {
          rs0 += __shfl_xor(rs0, mask);
          rs1 += __shfl_xor(rs1, mask);
          rs2 += __shfl_xor(rs2, mask);
          rs3 += __shfl_xor(rs3, mask);
        }
        if (lr == 0) {
          int ri = h * 128 + il;
          atomicAdd(&psum[ri],     rs0);
          atomicAdd(&psum[ri + 1], rs1);
          atomicAdd(&psum[ri + 2], rs2);
          atomicAdd(&psum[ri + 3], rs3);
        }
      }
    }
    barrier_asm();
    #pragma unroll
    for (int kk = 0; kk < 8; kk++) {     // flush 128 rows x 128 j, coalesced
      int idx = t + 256 * kk, row = idx >> 4, grp = idx & 15;
      u16x8 v = *(u16x8*)&T[row * TS + grp * 8];
      *(u16x8*)&Pm[((size_t)(b * Nn + i0 + h * 128 + row)) * 1024 + j0 + grp * 8] = v;
    }
  }
  __syncthreads();                       // drain LDS atomics before psum read
  rpart[((size_t)(b * 8) + (rem & 7)) * 1024 + i0 + t] = psum[t];
}

// ---------------------------------------------------------------------------
// pvout (128x128 tiles, 512 blocks, 2 blocks/CU, depth-2 ring):
// out = (VP @ Pm^T)/r + bias2 + proj_b + x.  XCD-swizzled block order so
// each XCD's L2 sees only 2 batches of VP/Pm panels.
__global__ __launch_bounds__(256, 2) void pvout_k(const u16* __restrict__ VP,
    const u16* __restrict__ Pm, const float* __restrict__ rpart,
    const float* __restrict__ bias2, const float* __restrict__ proj_b,
    const float* __restrict__ x, float* __restrict__ out) {
  __shared__ __align__(16) u16 SH[4 * SLOT128];   // 65536 B ring
  __shared__ float rinv[128];
  int bid = blockIdx.x;
  int u = (bid & 7) * 64 + (bid >> 3);   // bijective XCD swizzle (512 = 8*64)
  int b = u >> 5, rem = u & 31, m0 = (rem >> 3) * 128, i0 = (rem & 7) * 128;
  if (threadIdx.x < 128) {
    float s = 0.f;
    #pragma unroll
    for (int jb = 0; jb < 8; jb++)
      s += rpart[((size_t)(b * 8 + jb)) * 1024 + i0 + threadIdx.x];
    rinv[threadIdx.x] = 1.0f / s;
  }
  GEMM_PRE();
  core128(VP + ((size_t)(b * 512 + m0)) * 1024, 1024,
          Pm + ((size_t)(b * Nn + i0)) * 1024, 1024, 1024, SH, acc, wm, wn, quad, lr);
  __syncthreads();                       // rinv visible (writer waves may lag)
  #pragma unroll
  for (int fm = 0; fm < 4; fm++) {
    int m = m0 + wm + fm * 16 + quad * 4;
    float c0 = bias2[m    ] + proj_b[m    ];
    float c1 = bias2[m + 1] + proj_b[m + 1];
    float c2 = bias2[m + 2] + proj_b[m + 2];
    float c3 = bias2[m + 3] + proj_b[m + 3];
    #pragma unroll
    for (int fn = 0; fn < 4; fn++) {
      int il = wn + fn * 16 + lr;
      int i  = i0 + il;
      float ri = rinv[il];
      f32x4 a = acc[fm][fn];
      size_t o0 = ((size_t)(b * Cn + m)) * Nn + i;
      out[o0                  ] = a[0] * ri + c0 + x[o0                  ];
      out[o0 + Nn             ] = a[1] * ri + c1 + x[o0 + Nn             ];
      out[o0 + 2 * Nn         ] = a[2] * ri + c2 + x[o0 + 2 * Nn         ];
      out[o0 + 3 * (size_t)Nn] = a[3] * ri + c3 + x[o0 + 3 * (size_t)Nn];
    }
  }
}

// ---------------------------------------------------------------------------
extern "C" void kernel_launch(void* const* d_in, const int* in_sizes, int n_in,
                              void* d_out, int out_size, void* d_ws, size_t ws_size,
                              hipStream_t stream) {
  const float* x      = (const float*)d_in[0];
  const float* norm_w = (const float*)d_in[1];
  const float* norm_b = (const float*)d_in[2];
  const float* qkv_w  = (const float*)d_in[3];
  const float* qkv_b  = (const float*)d_in[4];
  const float* proj_w = (const float*)d_in[5];
  const float* proj_b = (const float*)d_in[6];
  float* out = (float*)d_out;
  char* ws = (char*)d_ws;

  u16*   wqk16 = (u16*)(ws);                     // 1024x512
  u16*   wvT16 = (u16*)(ws + 1048576);           // 512x512 (Wv^T)
  u16*   pw16  = (u16*)(ws + 1572864);           // 512x512
  u16*   W2    = (u16*)(ws + 2097152);           // 512x512 (= proj_w @ Wv)
  float* bias2 = (float*)(ws + 2621440);         // 512
  float* stats = (float*)(ws + 2623488);         // 256 raw sums (memset to 0)
  u16*   hT    = (u16*)(ws + 2624512);           // B*N*C
  u16*   qkT   = (u16*)(ws + 19401728);          // B*N*1024
  u16*   VP    = (u16*)(ws + 52956160);          // B*512*N
  u16*   Pm    = (u16*)(ws + 69733376);          // B*N*N
  float* rpart = (float*)(ws + 103287808);       // B*8*N

  hipMemsetAsync(stats, 0, 1024, stream);
  prep_k<<<1346, 256, 0, stream>>>(qkv_w, proj_w, qkv_b, x, wqk16, wvT16,
                                   pw16, bias2, stats);
  gnw2_k<<<2064, 256, 0, stream>>>(x, stats, norm_w, norm_b, pw16, wvT16,
                                   W2, hT);
  qkvp_k<<<768, 256, 0, stream>>>(wqk16, W2, hT, qkv_b, qkT, VP);
  qkexp_k<<<512, 256, 0, stream>>>(qkT, Pm, rpart);
  pvout_k<<<512, 256, 0, stream>>>(VP, Pm, rpart, bias2, proj_b, x, out);
}

// Round 5
// 212.197 us; speedup vs baseline: 1.0302x; 1.0302x over previous
//
#include <hip/hip_runtime.h>
#include <math.h>

#define Bn   16
#define Cn   512
#define Nn   1024
#define Gn   8
#define CPG  64
#define EPSf 1e-5f

typedef short           bf16x8 __attribute__((ext_vector_type(8)));
typedef float           f32x4  __attribute__((ext_vector_type(4)));
typedef unsigned short  u16;
typedef unsigned short  u16x4  __attribute__((ext_vector_type(4)));
typedef unsigned short  u16x8  __attribute__((ext_vector_type(8)));

#define TS 136   // LDS repack row stride (u16): 272B rows, 16B-aligned, 2-way banks

__device__ __forceinline__ u16 f2b(float f) {
  union { float f; unsigned u; } c; c.f = f;
  unsigned r = (c.u + 0x7FFFu + ((c.u >> 16) & 1u)) >> 16;
  return (u16)r;
}

// async 16B global -> LDS DMA; LDS dest = wave-uniform base + lane*16
__device__ __forceinline__ void g2l16(const void* g, void* l) {
  __builtin_amdgcn_global_load_lds(
      (const __attribute__((address_space(1))) unsigned int*)g,
      (__attribute__((address_space(3))) unsigned int*)l, 16, 0, 0);
}

// raw barrier: same instruction as __syncthreads but WITHOUT the compiler's
// s_waitcnt vmcnt(0) drain; "memory" clobber = compiler-level fence.
__device__ __forceinline__ void barrier_asm() {
  asm volatile("s_barrier" ::: "memory");
}

// ---------------------------------------------------------------------------
// OLD GEMM core (BK=32, 128x128, 4 waves): only used by gnw2's W2 GEMM now.
__device__ __forceinline__ void gemm_core(u16* As, u16* Bs,
    const u16* __restrict__ A, size_t sA,
    const u16* __restrict__ B, size_t sB, int K, f32x4 acc[4][4]) {
  const int t = threadIdx.x;
  const int w = t >> 6, l = t & 63, quad = l >> 4, lr = l & 15;
  const int wm = (w >> 1) * 64, wn = (w & 1) * 64;

  const int ra = w * 16 + (l >> 2);
  const int p  = l & 3;
  const int q  = p ^ ((ra >> 1) & 3);
  const u16* gA0 = A + (size_t)ra * sA + q * 8;
  const u16* gA1 = A + (size_t)(ra + 64) * sA + q * 8;
  const u16* gB0 = B + (size_t)ra * sB + q * 8;
  const u16* gB1 = B + (size_t)(ra + 64) * sB + q * 8;
  u16* lA0 = As + ra * 32 + p * 8;
  u16* lA1 = As + (ra + 64) * 32 + p * 8;
  u16* lB0 = Bs + ra * 32 + p * 8;
  u16* lB1 = Bs + (ra + 64) * 32 + p * 8;

  for (int k0 = 0; k0 < K; k0 += 32) {
    __syncthreads();
    g2l16(gA0 + k0, lA0);
    g2l16(gA1 + k0, lA1);
    g2l16(gB0 + k0, lB0);
    g2l16(gB1 + k0, lB1);
    __syncthreads();
    bf16x8 af[4], bfr[4];
    #pragma unroll
    for (int fm = 0; fm < 4; fm++) {
      int r = wm + fm * 16 + lr;
      af[fm] = *(const bf16x8*)&As[r * 32 + ((quad ^ ((r >> 1) & 3)) << 3)];
    }
    #pragma unroll
    for (int fn = 0; fn < 4; fn++) {
      int r = wn + fn * 16 + lr;
      bfr[fn] = *(const bf16x8*)&Bs[r * 32 + ((quad ^ ((r >> 1) & 3)) << 3)];
    }
    #pragma unroll
    for (int fm = 0; fm < 4; fm++)
      #pragma unroll
      for (int fn = 0; fn < 4; fn++)
        acc[fm][fn] = __builtin_amdgcn_mfma_f32_16x16x32_bf16(
            af[fm], bfr[fn], acc[fm][fn], 0, 0, 0);
  }
}

#define GEMM_PRE()                                              \
  const int t = threadIdx.x;                                    \
  const int w = t >> 6, l = t & 63, quad = l >> 4, lr = l & 15; \
  const int wm = (w >> 1) * 64, wn = (w & 1) * 64;              \
  (void)w; (void)wm; (void)wn; (void)l;                         \
  f32x4 acc[4][4];                                              \
  { f32x4 z = {0.f, 0.f, 0.f, 0.f};                             \
    for (int i_ = 0; i_ < 4; i_++)                              \
      for (int j_ = 0; j_ < 4; j_++) acc[i_][j_] = z; }

// ---------------------------------------------------------------------------
// core256: 256(m) x 128(n) block tile, 4 waves (2x2 grid of 128x64 wave
// tiles), BK=32, 3-slot LDS ring, depth-2 post-barrier staging, counted
// vmcnt(6), and a FINE 2-PHASE K-step (m196/m201-style interleave):
//   Ph1: vmcnt -> bar -> stage 3 loads -> 8 ds_read -> 16 MFMA (fm 0..3)
//   Ph2:          bar -> stage 3 loads -> 4 ds_read -> 16 MFMA (fm 4..7)
// sched_barrier(0) pins each phase so the compiler can't re-merge them.
//
// Ledger (unchanged from proven ring): stage targets slot t+2, whose last
// readers ran at step t-1; every wave passed the step-t Ph1 barrier only
// after its step t-1 reads+MFMAs, so staging after that barrier is safe.
// vmcnt: 6 loads/step total; at step-top, outstanding <= t-1's 6, so
// vmcnt(6) proves tile t landed; last steps drain with vmcnt(0).
#define SLOT 12288

__device__ __forceinline__ void core256(const u16* __restrict__ A, size_t sA,
    const u16* __restrict__ B, size_t sB, int K, u16* SH, f32x4 acc[8][4],
    int wm, int wn, int quad, int lr) {
  const int t = threadIdx.x, wv = t >> 6, l = t & 63;
  const int srow = l >> 2;                       // row-within-16-row chunk
  const int sch  = ((l & 3) ^ ((l >> 3) & 3)) * 8;  // pre-swizzled src chunk

  const u16* gA[4]; int lA[4];
  const u16* gB[2]; int lB[2];
  #pragma unroll
  for (int c = 0; c < 4; c++) {                  // A rows wv*64+c*16+srow
    gA[c] = A + (size_t)(wv * 64 + c * 16 + srow) * sA + sch;
    lA[c] = wv * 2048 + c * 512 + l * 8;         // = base + lane*16B: linear
  }
  #pragma unroll
  for (int c = 0; c < 2; c++) {                  // B rows wv*32+c*16+srow
    gB[c] = B + (size_t)(wv * 32 + c * 16 + srow) * sB + sch;
    lB[c] = 8192 + wv * 1024 + c * 512 + l * 8;
  }

  u16 *sc = SH, *sn = SH + SLOT, *sf = SH + 2 * SLOT;
  const int nt = K >> 5;
  // prologue: stage tile 0 -> slot0, tile 1 -> slot1
  #pragma unroll
  for (int c = 0; c < 4; c++) g2l16(gA[c], sc + lA[c]);
  #pragma unroll
  for (int c = 0; c < 2; c++) g2l16(gB[c], sc + lB[c]);
  if (nt > 1) {
    #pragma unroll
    for (int c = 0; c < 4; c++) g2l16(gA[c] + 32, sn + lA[c]);
    #pragma unroll
    for (int c = 0; c < 2; c++) g2l16(gB[c] + 32, sn + lB[c]);
  }

  const int rch = (quad ^ ((lr >> 1) & 3)) * 8;  // frag read chunk (swizzled)
  int aoff[8], boff[4];
  #pragma unroll
  for (int fm = 0; fm < 8; fm++) aoff[fm] = (wm + fm * 16 + lr) * 32 + rch;
  #pragma unroll
  for (int fn = 0; fn < 4; fn++) boff[fn] = 8192 + (wn + fn * 16 + lr) * 32 + rch;

  for (int tt = 0; tt < nt; tt++) {
    if (tt + 1 < nt) {                           // stage(t+1) may stay in flight
      asm volatile("s_waitcnt vmcnt(6)" ::: "memory");   // tile t landed
    } else {
      asm volatile("s_waitcnt vmcnt(0)" ::: "memory");
    }
    const int k0 = (tt + 2) * 32;
    const bool pf = (tt + 2 < nt);
    // ---- phase 1 ----
    barrier_asm();
    if (pf) {                                    // stage half of tile t+2
      g2l16(gA[0] + k0, sf + lA[0]);
      g2l16(gA[1] + k0, sf + lA[1]);
      g2l16(gA[2] + k0, sf + lA[2]);
    }
    bf16x8 af0[4], bfr[4];
    #pragma unroll
    for (int fm = 0; fm < 4; fm++) af0[fm] = *(const bf16x8*)&sc[aoff[fm]];
    #pragma unroll
    for (int fn = 0; fn < 4; fn++) bfr[fn] = *(const bf16x8*)&sc[boff[fn]];
    __builtin_amdgcn_s_setprio(1);
    #pragma unroll
    for (int fm = 0; fm < 4; fm++)
      #pragma unroll
      for (int fn = 0; fn < 4; fn++)
        acc[fm][fn] = __builtin_amdgcn_mfma_f32_16x16x32_bf16(
            af0[fm], bfr[fn], acc[fm][fn], 0, 0, 0);
    __builtin_amdgcn_s_setprio(0);
    __builtin_amdgcn_sched_barrier(0);
    // ---- phase 2 ----
    barrier_asm();
    if (pf) {                                    // stage rest of tile t+2
      g2l16(gA[3] + k0, sf + lA[3]);
      g2l16(gB[0] + k0, sf + lB[0]);
      g2l16(gB[1] + k0, sf + lB[1]);
    }
    bf16x8 af1[4];
    #pragma unroll
    for (int fm = 0; fm < 4; fm++) af1[fm] = *(const bf16x8*)&sc[aoff[fm + 4]];
    __builtin_amdgcn_s_setprio(1);
    #pragma unroll
    for (int fm = 0; fm < 4; fm++)
      #pragma unroll
      for (int fn = 0; fn < 4; fn++)
        acc[fm + 4][fn] = __builtin_amdgcn_mfma_f32_16x16x32_bf16(
            af1[fm], bfr[fn], acc[fm + 4][fn], 0, 0, 0);
    __builtin_amdgcn_s_setprio(0);
    __builtin_amdgcn_sched_barrier(0);
    u16* tmp = sc; sc = sn; sn = sf; sf = tmp;   // rotate ring
  }
}

#define CORE256_PRE()                                             \
  const int t = threadIdx.x;                                      \
  const int w = t >> 6, l = t & 63, quad = l >> 4, lr = l & 15;   \
  const int wm = (w >> 1) * 128, wn = (w & 1) * 64;               \
  (void)l;                                                        \
  f32x4 acc[8][4];                                                \
  { f32x4 z = {0.f, 0.f, 0.f, 0.f};                               \
    _Pragma("unroll")                                             \
    for (int i_ = 0; i_ < 8; i_++)                                \
      _Pragma("unroll")                                           \
      for (int j_ = 0; j_ < 4; j_++) acc[i_][j_] = z; }

// ---------------------------------------------------------------------------
// core128: 128x128 block tile, 4 waves (2x2 of 64x64), BK=32, 4-slot LDS
// ring, prefetch depth 2 (vmcnt(8)), single raw barrier per K-step, setprio.
#define SLOT128 8192   // u16 per slot: A[128][32] @0, B[128][32] @4096

__device__ __forceinline__ void core128(const u16* __restrict__ A, size_t sA,
    const u16* __restrict__ B, size_t sB, int K, u16* SH, f32x4 acc[4][4],
    int wm, int wn, int quad, int lr) {
  const int t = threadIdx.x;
  const int w = t >> 6, l = t & 63;
  const int ra = w * 16 + (l >> 2);              // [0,64)
  const int p  = l & 3;
  const int q  = p ^ ((ra >> 1) & 3);            // pre-swizzled src chunk
  const u16* gA0 = A + (size_t)ra * sA + q * 8;
  const u16* gA1 = A + (size_t)(ra + 64) * sA + q * 8;
  const u16* gB0 = B + (size_t)ra * sB + q * 8;
  const u16* gB1 = B + (size_t)(ra + 64) * sB + q * 8;
  const int lA0 = ra * 32 + p * 8;               // linear: wave base + lane*16B
  const int lA1 = (ra + 64) * 32 + p * 8;
  const int lB0 = 4096 + ra * 32 + p * 8;
  const int lB1 = 4096 + (ra + 64) * 32 + p * 8;

  const int nt = K >> 5;
  // prologue: stage tiles 0,1
  {
    u16* s0 = SH;
    g2l16(gA0, s0 + lA0); g2l16(gA1, s0 + lA1);
    g2l16(gB0, s0 + lB0); g2l16(gB1, s0 + lB1);
    if (nt > 1) {
      u16* s1 = SH + SLOT128;
      g2l16(gA0 + 32, s1 + lA0); g2l16(gA1 + 32, s1 + lA1);
      g2l16(gB0 + 32, s1 + lB0); g2l16(gB1 + 32, s1 + lB1);
    }
  }
  const int rch = (quad ^ ((lr >> 1) & 3)) * 8;  // frag read chunk (swizzled)
  int aoff[4], boff[4];
  #pragma unroll
  for (int fm = 0; fm < 4; fm++) aoff[fm] = (wm + fm * 16 + lr) * 32 + rch;
  #pragma unroll
  for (int fn = 0; fn < 4; fn++) boff[fn] = 4096 + (wn + fn * 16 + lr) * 32 + rch;

  for (int tt = 0; tt < nt; tt++) {
    u16* sc = SH + (tt & 3) * SLOT128;
    if (tt + 2 < nt) {                           // stage tile t+2
      u16* sn = SH + ((tt + 2) & 3) * SLOT128;
      const int k0 = (tt + 2) * 32;
      g2l16(gA0 + k0, sn + lA0); g2l16(gA1 + k0, sn + lA1);
      g2l16(gB0 + k0, sn + lB0); g2l16(gB1 + k0, sn + lB1);
      asm volatile("s_waitcnt vmcnt(8)" ::: "memory");   // tile t landed;
    } else if (tt + 1 < nt) {                            // t+1,t+2 in flight
      asm volatile("s_waitcnt vmcnt(4)" ::: "memory");
    } else {
      asm volatile("s_waitcnt vmcnt(0)" ::: "memory");
    }
    barrier_asm();                               // single barrier per K-step
    bf16x8 af[4], bfr[4];
    #pragma unroll
    for (int fm = 0; fm < 4; fm++) af[fm] = *(const bf16x8*)&sc[aoff[fm]];
    #pragma unroll
    for (int fn = 0; fn < 4; fn++) bfr[fn] = *(const bf16x8*)&sc[boff[fn]];
    __builtin_amdgcn_s_setprio(1);
    #pragma unroll
    for (int fm = 0; fm < 4; fm++)
      #pragma unroll
      for (int fn = 0; fn < 4; fn++)
        acc[fm][fn] = __builtin_amdgcn_mfma_f32_16x16x32_bf16(
            af[fm], bfr[fn], acc[fm][fn], 0, 0, 0);
    __builtin_amdgcn_s_setprio(0);
  }
}

// ---------------------------------------------------------------------------
// prep: [0,512) qk-weight cvt | [512,576) WvT transpose-cvt | [576,578) bias2
//       | [578,1090) gn-stats partial raw sums (atomic) | [1090,1346) proj_w cvt
__global__ __launch_bounds__(256) void prep_k(const float* __restrict__ qkv_w,
    const float* __restrict__ proj_w, const float* __restrict__ qkv_b,
    const float* __restrict__ x, u16* __restrict__ wqk16,
    u16* __restrict__ wvT16, u16* __restrict__ pw16,
    float* __restrict__ bias2, float* __restrict__ stats) {
  __shared__ u16 T[64][68];
  __shared__ float redf[8];
  int bid = blockIdx.x, t = threadIdx.x;
  if (bid < 512) {                       // q,k weights: 131072 float4 exact
    int i = bid * 256 + t;
    float4 v = ((const float4*)qkv_w)[i];
    u16x4 o;
    o.x = f2b(v.x); o.y = f2b(v.y); o.z = f2b(v.z); o.w = f2b(v.w);
    ((u16x4*)wqk16)[i] = o;
  } else if (bid < 576) {                // WvT[d][c] = Wv[c][d] bf16
    int tile = bid - 512, tx = tile & 7, ty = tile >> 3;
    int row = t >> 4, col4 = t & 15;
    #pragma unroll
    for (int it = 0; it < 4; it++) {
      int cc = row + it * 16;
      float4 v = *(const float4*)&qkv_w[(size_t)(1024 + ty * 64 + cc) * 512 + tx * 64 + col4 * 4];
      u16x4 o;
      o.x = f2b(v.x); o.y = f2b(v.y); o.z = f2b(v.z); o.w = f2b(v.w);
      *(u16x4*)&T[cc][col4 * 4] = o;
    }
    __syncthreads();
    #pragma unroll
    for (int it = 0; it < 2; it++) {
      int ch = t + it * 256;
      int d = ch >> 3, c8 = (ch & 7) * 8;
      u16x8 o;
      #pragma unroll
      for (int j = 0; j < 8; j++) o[j] = T[c8 + j][d];
      *(u16x8*)&wvT16[(size_t)(tx * 64 + d) * 512 + ty * 64 + c8] = o;
    }
  } else if (bid < 578) {                // bias2 = proj_w @ v_bias (fp32 exact)
    int m = (bid - 576) * 256 + t;
    float s = 0.f;
    for (int c = 0; c < 512; c++)
      s += proj_w[(size_t)m * 512 + c] * qkv_b[1024 + c];
    bias2[m] = s;
  } else if (bid < 1090) {               // gn raw-sum partials: 4 blocks/(b,g)
    int idx = bid - 578, bg = idx >> 2, part = idx & 3;
    const float4* xp = (const float4*)x + (size_t)bg * 16384 + part * 4096;
    float s = 0.f, ss = 0.f;
    for (int i = t; i < 4096; i += 256) {
      float4 v = xp[i];
      s  += v.x + v.y + v.z + v.w;
      ss += v.x * v.x + v.y * v.y + v.z * v.z + v.w * v.w;
    }
    #pragma unroll
    for (int off = 32; off > 0; off >>= 1) {
      s  += __shfl_down(s, off);
      ss += __shfl_down(ss, off);
    }
    int lane = t & 63, wid = t >> 6;
    if (lane == 0) { redf[wid] = s; redf[4 + wid] = ss; }
    __syncthreads();
    if (t == 0) {
      atomicAdd(&stats[bg],       redf[0] + redf[1] + redf[2] + redf[3]);
      atomicAdd(&stats[128 + bg], redf[4] + redf[5] + redf[6] + redf[7]);
    }
  } else {                               // proj_w cvt: 65536 float4
    int i = (bid - 1090) * 256 + t;
    float4 v = ((const float4*)proj_w)[i];
    u16x4 o;
    o.x = f2b(v.x); o.y = f2b(v.y); o.z = f2b(v.z); o.w = f2b(v.w);
    ((u16x4*)pw16)[i] = o;
  }
}

// ---------------------------------------------------------------------------
// gnw2: [0,16) W2 = pw16 @ Wv | [16,2064) gn apply+transpose (raw-sum stats)
__global__ __launch_bounds__(256) void gnw2_k(const float* __restrict__ x,
    const float* __restrict__ stats, const float* __restrict__ nw,
    const float* __restrict__ nb, const u16* __restrict__ pw16,
    const u16* __restrict__ wvT16, u16* __restrict__ W2, u16* __restrict__ hT) {
  __shared__ u16 AsBs[8192];
  int bid = blockIdx.x;
  if (bid < 16) {
    int m0 = (bid >> 2) * 128, d0 = (bid & 3) * 128;
    GEMM_PRE();
    gemm_core(AsBs, AsBs + 4096, pw16 + (size_t)m0 * 512, 512,
              wvT16 + (size_t)d0 * 512, 512, 512, acc);
    #pragma unroll
    for (int fm = 0; fm < 4; fm++) {
      int m = m0 + wm + fm * 16 + quad * 4;
      #pragma unroll
      for (int fn = 0; fn < 4; fn++) {
        int d = d0 + wn + fn * 16 + lr;
        f32x4 a = acc[fm][fn];
        W2[(size_t)(m    ) * 512 + d] = f2b(a[0]);
        W2[(size_t)(m + 1) * 512 + d] = f2b(a[1]);
        W2[(size_t)(m + 2) * 512 + d] = f2b(a[2]);
        W2[(size_t)(m + 3) * 512 + d] = f2b(a[3]);
      }
    }
    return;
  }
  int u = bid - 16;                      // 2048 tiles: 64c x 64n
  int b = u >> 7, rem = u & 127, c0 = (rem >> 4) * 64, n0 = (rem & 15) * 64;
  u16 (*T)[68] = (u16(*)[68])AsBs;
  int t = threadIdx.x;
  int row = t >> 4, col4 = t & 15;
  const float inv = 1.0f / 65536.0f;
  #pragma unroll
  for (int it = 0; it < 4; it++) {
    int cc = row + it * 16;
    int c  = c0 + cc;
    int bg = b * Gn + (c >> 6);
    float mean = stats[bg] * inv;
    float var  = stats[128 + bg] * inv - mean * mean;
    float rstd = rsqrtf(var + EPSf);
    float a  = nw[c] * rstd;
    float bb = nb[c] - mean * a;
    float4 xv = *(const float4*)&x[((size_t)(b * Cn + c)) * Nn + n0 + col4 * 4];
    u16x4 o;
    o.x = f2b(xv.x * a + bb); o.y = f2b(xv.y * a + bb);
    o.z = f2b(xv.z * a + bb); o.w = f2b(xv.w * a + bb);
    *(u16x4*)&T[cc][col4 * 4] = o;
  }
  __syncthreads();
  #pragma unroll
  for (int it = 0; it < 2; it++) {
    int ch = t + it * 256;
    int n  = ch >> 3, c8 = (ch & 7) * 8;
    u16x8 o;
    #pragma unroll
    for (int j = 0; j < 8; j++) o[j] = T[c8 + j][n];
    *(u16x8*)&hT[((size_t)(b * Nn + n0 + n)) * 512 + c0 + c8] = o;
  }
}

// ---------------------------------------------------------------------------
// qkvp (256x128 tiles, 768 blocks, XCD-swizzled):
//   u<512:   qkT[b][n][m] = wqk.h + bias : 16b x 4 m-tiles(256) x 8 n-tiles(128)
//   u>=512:  VP = W2 @ h               : 16b x 2 m-tiles(256) x 8 j-tiles(128)
__global__ __launch_bounds__(256, 2) void qkvp_k(const u16* __restrict__ wqk16,
    const u16* __restrict__ W2, const u16* __restrict__ hT,
    const float* __restrict__ qkv_b, u16* __restrict__ qkT,
    u16* __restrict__ VP) {
  __shared__ __align__(16) u16 SH[3 * SLOT];   // 73728 B: ring + epilogue T
  int bid = blockIdx.x;
  int u = (bid & 7) * 96 + (bid >> 3);   // bijective XCD swizzle (768 = 8*96)
  CORE256_PRE();

  if (u < 512) {                         // ---- qkT: transpose-store epilogue
    int b = u >> 5, rem = u & 31, m0 = (rem >> 3) * 256, n0 = (rem & 7) * 128;
    core256(wqk16 + (size_t)m0 * 512, 512,
            hT + (size_t)(b * Nn + n0) * 512, 512, 512, SH, acc, wm, wn, quad, lr);
    float4 bss[8];
    #pragma unroll
    for (int fm = 0; fm < 8; fm++)
      bss[fm] = *(const float4*)&qkv_b[m0 + wm + fm * 16 + quad * 4];
    u16* T = SH;                         // overlay [64 n][264 m-stride] u16
    const int hsel = wn >> 6;            // which n-half this wave owns
    #pragma unroll
    for (int h = 0; h < 2; h++) {
      barrier_asm();                     // (first one also closes the K-loop)
      if (hsel == h) {
        #pragma unroll
        for (int fm = 0; fm < 8; fm++) {
          int mc = wm + fm * 16 + quad * 4;
          #pragma unroll
          for (int fn = 0; fn < 4; fn++) {
            int nl = fn * 16 + lr;
            f32x4 a = acc[fm][fn];
            u16x4 pk;
            pk.x = f2b(a[0] + bss[fm].x); pk.y = f2b(a[1] + bss[fm].y);
            pk.z = f2b(a[2] + bss[fm].z); pk.w = f2b(a[3] + bss[fm].w);
            *(u16x4*)&T[nl * 264 + mc] = pk;   // T[n][m], 264-stride (2-way banks)
          }
        }
      }
      barrier_asm();
      #pragma unroll
      for (int kk = 0; kk < 8; kk++) {   // flush 64 rows x 256 m, coalesced
        int idx = t + 256 * kk, row = idx >> 5, grp = idx & 31;
        u16x8 v = *(u16x8*)&T[row * 264 + grp * 8];
        *(u16x8*)&qkT[((size_t)(b * Nn + n0 + h * 64 + row)) * 1024 + m0 + grp * 8] = v;
      }
    }
  } else {                               // ---- VP: natural-store epilogue
    int u2 = u - 512;
    int b = u2 >> 4, rem = u2 & 15, m0 = (rem >> 3) * 256, j0 = (rem & 7) * 128;
    core256(W2 + (size_t)m0 * 512, 512,
            hT + (size_t)(b * Nn + j0) * 512, 512, 512, SH, acc, wm, wn, quad, lr);
    u16* T = SH;                         // overlay [128 m][TS] u16
    const int hsel = wm >> 7;            // which m-half this wave owns
    #pragma unroll
    for (int h = 0; h < 2; h++) {
      barrier_asm();
      if (hsel == h) {
        #pragma unroll
        for (int fm = 0; fm < 8; fm++) {
          int ml = fm * 16 + quad * 4;   // m within 128-half
          #pragma unroll
          for (int fn = 0; fn < 4; fn++) {
            int jl = wn + fn * 16 + lr;
            f32x4 a = acc[fm][fn];
            T[(ml    ) * TS + jl] = f2b(a[0]);
            T[(ml + 1) * TS + jl] = f2b(a[1]);
            T[(ml + 2) * TS + jl] = f2b(a[2]);
            T[(ml + 3) * TS + jl] = f2b(a[3]);
          }
        }
      }
      barrier_asm();
      #pragma unroll
      for (int kk = 0; kk < 8; kk++) {   // flush 128 rows x 128 j, coalesced
        int idx = t + 256 * kk, row = idx >> 4, grp = idx & 15;
        u16x8 v = *(u16x8*)&T[row * TS + grp * 8];
        *(u16x8*)&VP[((size_t)(b * 512 + m0 + h * 128 + row)) * 1024 + j0 + grp * 8] = v;
      }
    }
  }
}

// ---------------------------------------------------------------------------
// qkexp (256x128 tiles, 512 blocks, XCD-swizzled): Pm = exp(scale*q.k) bf16;
// rpart partial row sums. exp computed ONCE per element, fused into the
// half-tile repack phase. No max subtraction: logits ~ N(0,1).
__global__ __launch_bounds__(256, 2) void qkexp_k(const u16* __restrict__ qkT,
    u16* __restrict__ Pm, float* __restrict__ rpart) {
  __shared__ __align__(16) u16 SH[3 * SLOT];
  __shared__ float psum[256];
  int bid = blockIdx.x;
  int u = (bid & 7) * 64 + (bid >> 3);   // bijective XCD swizzle (512 = 8*64)
  int b = u >> 5, rem = u & 31, i0 = (rem >> 3) * 256, j0 = (rem & 7) * 128;
  const u16* base = qkT + (size_t)b * Nn * 1024;
  CORE256_PRE();
  core256(base + (size_t)i0 * 1024, 1024,
          base + (size_t)j0 * 1024 + 512, 1024, 512, SH, acc, wm, wn, quad, lr);
  psum[t] = 0.f;
  const float scale = 0.04419417382415922f;  // 512^-0.5
  u16* T = SH;                           // overlay [128 i][TS] u16
  const int hsel = wm >> 7;              // which i-half this wave owns
  #pragma unroll
  for (int h = 0; h < 2; h++) {
    barrier_asm();                       // protects T reuse AND psum init
    if (hsel == h) {
      #pragma unroll
      for (int fm = 0; fm < 8; fm++) {
        int il = fm * 16 + quad * 4;     // i within 128-half
        float rs0 = 0.f, rs1 = 0.f, rs2 = 0.f, rs3 = 0.f;
        #pragma unroll
        for (int fn = 0; fn < 4; fn++) {
          int jl = wn + fn * 16 + lr;
          f32x4 a = acc[fm][fn];
          float e0 = __expf(a[0] * scale);
          float e1 = __expf(a[1] * scale);
          float e2 = __expf(a[2] * scale);
          float e3 = __expf(a[3] * scale);
          rs0 += e0; rs1 += e1; rs2 += e2; rs3 += e3;
          T[(il    ) * TS + jl] = f2b(e0);
          T[(il + 1) * TS + jl] = f2b(e1);
          T[(il + 2) * TS + jl] = f2b(e2);
          T[(il + 3) * TS + jl] = f2b(e3);
        }
        #pragma unroll
        for (int mask = 1; mask < 16; mask <<= 1) {
          rs0 += __shfl_xor(rs0, mask);
          rs1 += __shfl_xor(rs1, mask);
          rs2 += __shfl_xor(rs2, mask);
          rs3 += __shfl_xor(rs3, mask);
        }
        if (lr == 0) {
          int ri = h * 128 + il;
          atomicAdd(&psum[ri],     rs0);
          atomicAdd(&psum[ri + 1], rs1);
          atomicAdd(&psum[ri + 2], rs2);
          atomicAdd(&psum[ri + 3], rs3);
        }
      }
    }
    barrier_asm();
    #pragma unroll
    for (int kk = 0; kk < 8; kk++) {     // flush 128 rows x 128 j, coalesced
      int idx = t + 256 * kk, row = idx >> 4, grp = idx & 15;
      u16x8 v = *(u16x8*)&T[row * TS + grp * 8];
      *(u16x8*)&Pm[((size_t)(b * Nn + i0 + h * 128 + row)) * 1024 + j0 + grp * 8] = v;
    }
  }
  __syncthreads();                       // drain LDS atomics before psum read
  rpart[((size_t)(b * 8) + (rem & 7)) * 1024 + i0 + t] = psum[t];
}

// ---------------------------------------------------------------------------
// pvout (128x128 tiles, 512 blocks, 2 blocks/CU, depth-2 ring):
// out = (VP @ Pm^T)/r + bias2 + proj_b + x.  XCD-swizzled block order so
// each XCD's L2 sees only 2 batches of VP/Pm panels.
__global__ __launch_bounds__(256, 2) void pvout_k(const u16* __restrict__ VP,
    const u16* __restrict__ Pm, const float* __restrict__ rpart,
    const float* __restrict__ bias2, const float* __restrict__ proj_b,
    const float* __restrict__ x, float* __restrict__ out) {
  __shared__ __align__(16) u16 SH[4 * SLOT128];   // 65536 B ring
  __shared__ float rinv[128];
  int bid = blockIdx.x;
  int u = (bid & 7) * 64 + (bid >> 3);   // bijective XCD swizzle (512 = 8*64)
  int b = u >> 5, rem = u & 31, m0 = (rem >> 3) * 128, i0 = (rem & 7) * 128;
  if (threadIdx.x < 128) {
    float s = 0.f;
    #pragma unroll
    for (int jb = 0; jb < 8; jb++)
      s += rpart[((size_t)(b * 8 + jb)) * 1024 + i0 + threadIdx.x];
    rinv[threadIdx.x] = 1.0f / s;
  }
  GEMM_PRE();
  core128(VP + ((size_t)(b * 512 + m0)) * 1024, 1024,
          Pm + ((size_t)(b * Nn + i0)) * 1024, 1024, 1024, SH, acc, wm, wn, quad, lr);
  __syncthreads();                       // rinv visible (writer waves may lag)
  #pragma unroll
  for (int fm = 0; fm < 4; fm++) {
    int m = m0 + wm + fm * 16 + quad * 4;
    float c0 = bias2[m    ] + proj_b[m    ];
    float c1 = bias2[m + 1] + proj_b[m + 1];
    float c2 = bias2[m + 2] + proj_b[m + 2];
    float c3 = bias2[m + 3] + proj_b[m + 3];
    #pragma unroll
    for (int fn = 0; fn < 4; fn++) {
      int il = wn + fn * 16 + lr;
      int i  = i0 + il;
      float ri = rinv[il];
      f32x4 a = acc[fm][fn];
      size_t o0 = ((size_t)(b * Cn + m)) * Nn + i;
      out[o0                  ] = a[0] * ri + c0 + x[o0                  ];
      out[o0 + Nn             ] = a[1] * ri + c1 + x[o0 + Nn             ];
      out[o0 + 2 * Nn         ] = a[2] * ri + c2 + x[o0 + 2 * Nn         ];
      out[o0 + 3 * (size_t)Nn] = a[3] * ri + c3 + x[o0 + 3 * (size_t)Nn];
    }
  }
}

// ---------------------------------------------------------------------------
extern "C" void kernel_launch(void* const* d_in, const int* in_sizes, int n_in,
                              void* d_out, int out_size, void* d_ws, size_t ws_size,
                              hipStream_t stream) {
  const float* x      = (const float*)d_in[0];
  const float* norm_w = (const float*)d_in[1];
  const float* norm_b = (const float*)d_in[2];
  const float* qkv_w  = (const float*)d_in[3];
  const float* qkv_b  = (const float*)d_in[4];
  const float* proj_w = (const float*)d_in[5];
  const float* proj_b = (const float*)d_in[6];
  float* out = (float*)d_out;
  char* ws = (char*)d_ws;

  u16*   wqk16 = (u16*)(ws);                     // 1024x512
  u16*   wvT16 = (u16*)(ws + 1048576);           // 512x512 (Wv^T)
  u16*   pw16  = (u16*)(ws + 1572864);           // 512x512
  u16*   W2    = (u16*)(ws + 2097152);           // 512x512 (= proj_w @ Wv)
  float* bias2 = (float*)(ws + 2621440);         // 512
  float* stats = (float*)(ws + 2623488);         // 256 raw sums (memset to 0)
  u16*   hT    = (u16*)(ws + 2624512);           // B*N*C
  u16*   qkT   = (u16*)(ws + 19401728);          // B*N*1024
  u16*   VP    = (u16*)(ws + 52956160);          // B*512*N
  u16*   Pm    = (u16*)(ws + 69733376);          // B*N*N
  float* rpart = (float*)(ws + 103287808);       // B*8*N

  hipMemsetAsync(stats, 0, 1024, stream);
  prep_k<<<1346, 256, 0, stream>>>(qkv_w, proj_w, qkv_b, x, wqk16, wvT16,
                                   pw16, bias2, stats);
  gnw2_k<<<2064, 256, 0, stream>>>(x, stats, norm_w, norm_b, pw16, wvT16,
                                   W2, hT);
  qkvp_k<<<768, 256, 0, stream>>>(wqk16, W2, hT, qkv_b, qkT, VP);
  qkexp_k<<<512, 256, 0, stream>>>(qkT, Pm, rpart);
  pvout_k<<<512, 256, 0, stream>>>(VP, Pm, rpart, bias2, proj_b, x, out);
}